// Round 1
// baseline (402.062 us; speedup 1.0000x reference)
//
#include <hip/hip_runtime.h>
#include <cstdint>
#include <cstddef>

// Problem constants (fixed by the reference)
#define N_ROWS 4096
#define DIM    512
#define NCLS   30000
#define NTILES 235                 // ceil(30000/128)
#define CPAD   (NTILES * 128)      // 30080, padded classes (zero rows -> exp ~ 0)
#define GROUPS 24                  // class-split groups
#define NPART  (GROUPS * 2)        // partials per row: group x wave-col
#define BM 128
#define BN 128
#define BK 64

typedef float  f32x4  __attribute__((ext_vector_type(4)));
typedef short  bf16x8 __attribute__((ext_vector_type(8)));
typedef unsigned int   u32;
typedef unsigned short u16;

// ---- workspace layout (bytes) ----
#define WB_BYTES   ((size_t)CPAD * DIM * 2)          // 30,801,920
#define EB_BYTES   ((size_t)N_ROWS * DIM * 2)        //  4,194,304
#define PSUM_BYTES ((size_t)NPART * N_ROWS * 4)      //    786,432
#define LL_BYTES   ((size_t)N_ROWS * 4)
#define BL_BYTES   (64 * 4)
#define LAB_BYTES  ((size_t)N_ROWS * 4)

__device__ __forceinline__ u16 f2bf(float f) {  // RNE float->bf16
  u32 x = __builtin_bit_cast(u32, f);
  x += 0x7fffu + ((x >> 16) & 1u);
  return (u16)(x >> 16);
}

__device__ __forceinline__ void gl_lds16(const u16* g, u16* l) {
  __builtin_amdgcn_global_load_lds((const __attribute__((address_space(1))) u32*)g,
                                   (__attribute__((address_space(3))) u32*)l,
                                   16, 0, 0);
}

// ---- label dtype probe: int64 stored little-endian reads as [lo,0,lo,0,...] ----
__global__ void lab_detect(const int* __restrict__ lab, int* __restrict__ flag) {
  __shared__ int s_nz;
  int tid = threadIdx.x;
  if (tid == 0) s_nz = 0;
  __syncthreads();
  int nz = 0;
  for (int i = tid; i < N_ROWS / 2; i += 1024) nz |= lab[2 * i + 1];
  if (nz) atomicOr(&s_nz, 1);
  __syncthreads();
  if (tid == 0) *flag = (s_nz == 0) ? 1 : 0;   // 1 -> int64 layout
}

__global__ void lab_fix(const int* __restrict__ lab, const int* __restrict__ flag,
                        int* __restrict__ out) {
  int i = blockIdx.x * 256 + threadIdx.x;
  out[i] = flag[0] ? lab[2 * i] : lab[i];
}

// ---- W: L2-normalize rows + cast bf16; pad rows [NCLS,CPAD) with zeros ----
__global__ void prep_w(const float* __restrict__ w, u16* __restrict__ wb) {
  int wv   = threadIdx.x >> 6;
  int lane = threadIdx.x & 63;
  int c = blockIdx.x * 4 + wv;              // one wave per class row
  u16* dst = wb + (size_t)c * DIM + lane * 8;
  if (c >= NCLS) {
    *(uint4*)dst = make_uint4(0, 0, 0, 0);
    return;
  }
  const float* src = w + (size_t)c * DIM + lane * 8;
  float4 v0 = *(const float4*)src;
  float4 v1 = *(const float4*)(src + 4);
  float a[8] = {v0.x, v0.y, v0.z, v0.w, v1.x, v1.y, v1.z, v1.w};
  float ss = 0.f;
  #pragma unroll
  for (int i = 0; i < 8; i++) ss += a[i] * a[i];
  #pragma unroll
  for (int off = 32; off; off >>= 1) ss += __shfl_xor(ss, off, 64);
  float inv = 1.0f / fmaxf(sqrtf(ss), 1e-12f);
  union { u16 h[8]; uint4 q; } pk;
  #pragma unroll
  for (int i = 0; i < 8; i++) pk.h[i] = f2bf(a[i] * inv);
  *(uint4*)dst = pk.q;
}

// ---- E: cast bf16 ----
__global__ void prep_e(const float* __restrict__ e, u16* __restrict__ eb) {
  size_t idx = ((size_t)blockIdx.x * 256 + threadIdx.x) * 8;
  float4 v0 = *(const float4*)(e + idx);
  float4 v1 = *(const float4*)(e + idx + 4);
  float a[8] = {v0.x, v0.y, v0.z, v0.w, v1.x, v1.y, v1.z, v1.w};
  union { u16 h[8]; uint4 q; } pk;
  #pragma unroll
  for (int i = 0; i < 8; i++) pk.h[i] = f2bf(a[i]);
  *(uint4*)(eb + idx) = pk.q;
}

// ---- fused GEMM + clip + margin + partial sum-exp (fixed max = 64) ----
__global__ __launch_bounds__(256) void arc_main(
    const u16* __restrict__ eb, const u16* __restrict__ wb,
    const int* __restrict__ labels, float* __restrict__ psum,
    float* __restrict__ ll)
{
  __shared__ u16 lA[BM * BK];
  __shared__ u16 lB[BN * BK];
  const int tid  = threadIdx.x;
  const int lane = tid & 63;
  const int wv   = tid >> 6;
  const int wr   = wv >> 1;       // wave row (0..1): 64 emb rows each
  const int wc   = wv & 1;        // wave col (0..1): 64 classes each
  const int rb   = blockIdx.x & 31;
  const int g    = blockIdx.x >> 5;     // class group 0..GROUPS-1
  const int rowbase = rb * BM;
  const int rgrp = (lane >> 4) * 4;     // D-frag row group
  const int cl   = lane & 15;           // D-frag col / A,B row-col lane

  int lbl[4][4];
  #pragma unroll
  for (int m = 0; m < 4; m++)
    #pragma unroll
    for (int j = 0; j < 4; j++)
      lbl[m][j] = labels[rowbase + wr * 64 + m * 16 + rgrp + j];

  float srun[4][4];
  #pragma unroll
  for (int m = 0; m < 4; m++)
    #pragma unroll
    for (int j = 0; j < 4; j++) srun[m][j] = 0.f;

  const int ldrow = lane >> 3;        // 0..7 within 8-row chunk
  const int ldk   = (lane & 7) * 8;   // k element offset (16B per lane)

  const float CLIP_HI = 1.0f - 1e-7f;
  const float CLIP_LO = -1.0f + 1e-7f;
  const float COSM = 0.8775825618903728f;   // cos(0.5)
  const float SINM = 0.4794255386042030f;   // sin(0.5)
  const float K1   = 92.33248261972189f;    // 64*log2(e):  exp(l-64)=2^((t-1)*K1)

  for (int t = g; t < NTILES; t += GROUPS) {
    const int cb = t * BN;
    f32x4 acc[4][4];
    #pragma unroll
    for (int m = 0; m < 4; m++)
      #pragma unroll
      for (int n = 0; n < 4; n++)
        #pragma unroll
        for (int q = 0; q < 4; q++) acc[m][n][q] = 0.f;

    for (int kt = 0; kt < DIM / BK; kt++) {
      const int k0 = kt * BK;
      #pragma unroll
      for (int i = 0; i < 4; i++) {
        const int chunk = wv * 4 + i;            // 16 chunks of 1KB per tile
        const int row   = chunk * 8 + ldrow;
        gl_lds16(eb + (size_t)(rowbase + row) * DIM + k0 + ldk, &lA[chunk * 512]);
        gl_lds16(wb + (size_t)(cb      + row) * DIM + k0 + ldk, &lB[chunk * 512]);
      }
      __syncthreads();   // drains vmcnt before barrier (compiler-enforced)
      #pragma unroll
      for (int kk = 0; kk < 2; kk++) {
        bf16x8 af[4], bg[4];
        #pragma unroll
        for (int m = 0; m < 4; m++)
          af[m] = *(const bf16x8*)&lA[(wr * 64 + m * 16 + cl) * BK + kk * 32 + (lane >> 4) * 8];
        #pragma unroll
        for (int n = 0; n < 4; n++)
          bg[n] = *(const bf16x8*)&lB[(wc * 64 + n * 16 + cl) * BK + kk * 32 + (lane >> 4) * 8];
        #pragma unroll
        for (int m = 0; m < 4; m++)
          #pragma unroll
          for (int n = 0; n < 4; n++)
            acc[m][n] = __builtin_amdgcn_mfma_f32_16x16x32_bf16(af[m], bg[n], acc[m][n], 0, 0, 0);
      }
      __syncthreads();
    }

    // epilogue: clip, margin-at-label, accumulate exp(logit-64)
    #pragma unroll
    for (int n = 0; n < 4; n++) {
      const int cidx = cb + wc * 64 + n * 16 + cl;
      #pragma unroll
      for (int m = 0; m < 4; m++) {
        #pragma unroll
        for (int j = 0; j < 4; j++) {
          float v  = acc[m][n][j];
          float tc = fminf(fmaxf(v, CLIP_LO), CLIP_HI);
          float tv = tc;
          if (lbl[m][j] == cidx) {
            float sq = __builtin_amdgcn_sqrtf(fmaxf(1.0f - tc * tc, 0.0f));
            tv = tc * COSM - sq * SINM;
            ll[rowbase + wr * 64 + m * 16 + rgrp + j] = tv * 64.0f;
          }
          srun[m][j] += __builtin_amdgcn_exp2f((tv - 1.0f) * K1);
        }
      }
    }
  }

  // reduce partial sums across the 16 col-lanes, write one partial per row
  #pragma unroll
  for (int m = 0; m < 4; m++) {
    #pragma unroll
    for (int j = 0; j < 4; j++) {
      float s = srun[m][j];
      s += __shfl_xor(s, 1, 64);
      s += __shfl_xor(s, 2, 64);
      s += __shfl_xor(s, 4, 64);
      s += __shfl_xor(s, 8, 64);
      if (cl == 0)
        psum[(size_t)(g * 2 + wc) * N_ROWS + rowbase + wr * 64 + m * 16 + rgrp + j] = s;
    }
  }
}

// ---- per-row LSE merge + per-block loss sums ----
__global__ void arc_finish1(const float* __restrict__ psum, const float* __restrict__ ll,
                            float* __restrict__ bl) {
  int tid = threadIdx.x;
  int row = blockIdx.x * 256 + tid;
  float S = 0.f;
  #pragma unroll
  for (int p = 0; p < NPART; p++) S += psum[(size_t)p * N_ROWS + row];
  float loss = 64.0f + __builtin_amdgcn_logf(S) * 0.6931471805599453f - ll[row];
  #pragma unroll
  for (int off = 32; off; off >>= 1) loss += __shfl_xor(loss, off, 64);
  __shared__ float red[4];
  if ((tid & 63) == 0) red[tid >> 6] = loss;
  __syncthreads();
  if (tid == 0) bl[blockIdx.x] = red[0] + red[1] + red[2] + red[3];
}

__global__ void arc_finish2(const float* __restrict__ bl, float* __restrict__ out) {
  if (threadIdx.x == 0) {
    float t = 0.f;
    for (int i = 0; i < N_ROWS / 256; i++) t += bl[i];
    out[0] = t * (1.0f / (float)N_ROWS);
  }
}

extern "C" void kernel_launch(void* const* d_in, const int* in_sizes, int n_in,
                              void* d_out, int out_size, void* d_ws, size_t ws_size,
                              hipStream_t stream) {
  const float* emb   = (const float*)d_in[0];
  const int*   lab   = (const int*)d_in[1];
  const float* wts   = (const float*)d_in[2];

  char* ws = (char*)d_ws;
  u16*   wb    = (u16*)(ws);
  u16*   eb    = (u16*)(ws + WB_BYTES);
  float* psum  = (float*)(ws + WB_BYTES + EB_BYTES);
  float* ll    = (float*)(ws + WB_BYTES + EB_BYTES + PSUM_BYTES);
  float* bl    = (float*)(ws + WB_BYTES + EB_BYTES + PSUM_BYTES + LL_BYTES);
  int*   lab32 = (int*)  (ws + WB_BYTES + EB_BYTES + PSUM_BYTES + LL_BYTES + BL_BYTES);
  int*   flag  = (int*)  (ws + WB_BYTES + EB_BYTES + PSUM_BYTES + LL_BYTES + BL_BYTES + LAB_BYTES);
  // total ~34.2 MiB of d_ws assumed available

  lab_detect<<<dim3(1), dim3(1024), 0, stream>>>(lab, flag);
  lab_fix<<<dim3(N_ROWS / 256), dim3(256), 0, stream>>>(lab, flag, lab32);
  prep_w<<<dim3(CPAD / 4), dim3(256), 0, stream>>>(wts, wb);
  prep_e<<<dim3((N_ROWS * DIM / 8) / 256), dim3(256), 0, stream>>>(emb, eb);
  arc_main<<<dim3(32 * GROUPS), dim3(256), 0, stream>>>(eb, wb, lab32, psum, ll);
  arc_finish1<<<dim3(N_ROWS / 256), dim3(256), 0, stream>>>(psum, ll, bl);
  arc_finish2<<<dim3(1), dim3(64), 0, stream>>>(bl, (float*)d_out);
}

// Round 2
// 395.286 us; speedup vs baseline: 1.0171x; 1.0171x over previous
//
#include <hip/hip_runtime.h>
#include <cstdint>
#include <cstddef>

// Problem constants (fixed by the reference)
#define N_ROWS 4096
#define DIM    512
#define NCLS   30000
#define NTILES 235                 // ceil(30000/128)
#define CPAD   (NTILES * 128)      // 30080, padded classes (zero rows -> exp ~ 0)
#define GROUPS 47                  // 235 = 47*5 -> perfect balance
#define NPART  (GROUPS * 2)        // partials per row: group x wave-col
#define BM 128
#define BN 128
#define BK 64
#define TILES_PER_BLOCK 5
#define NSTEPS (TILES_PER_BLOCK * (DIM / BK))   // 40

typedef float  f32x4  __attribute__((ext_vector_type(4)));
typedef short  bf16x8 __attribute__((ext_vector_type(8)));
typedef unsigned int   u32;
typedef unsigned short u16;

// ---- workspace layout (bytes) ----
#define WB_BYTES   ((size_t)CPAD * DIM * 2)          // 30,801,920
#define EB_BYTES   ((size_t)N_ROWS * DIM * 2)        //  4,194,304
#define PSUM_BYTES ((size_t)NPART * N_ROWS * 4)      //  1,540,096
#define LL_BYTES   ((size_t)N_ROWS * 4)
#define BL_BYTES   (64 * 4)
#define LAB_BYTES  ((size_t)N_ROWS * 4)

__device__ __forceinline__ u16 f2bf(float f) {  // RNE float->bf16
  u32 x = __builtin_bit_cast(u32, f);
  x += 0x7fffu + ((x >> 16) & 1u);
  return (u16)(x >> 16);
}

__device__ __forceinline__ void gl_lds16(const u16* g, u16* l) {
  __builtin_amdgcn_global_load_lds((const __attribute__((address_space(1))) u32*)g,
                                   (__attribute__((address_space(3))) u32*)l,
                                   16, 0, 0);
}

// ---- label dtype probe: int64 little-endian reads as [lo,0,lo,0,...] ----
__global__ void lab_detect(const int* __restrict__ lab, int* __restrict__ flag) {
  __shared__ int s_nz;
  int tid = threadIdx.x;
  if (tid == 0) s_nz = 0;
  __syncthreads();
  int nz = 0;
  for (int i = tid; i < N_ROWS / 2; i += 1024) nz |= lab[2 * i + 1];
  if (nz) atomicOr(&s_nz, 1);
  __syncthreads();
  if (tid == 0) *flag = (s_nz == 0) ? 1 : 0;   // 1 -> int64 layout
}

__global__ void lab_fix(const int* __restrict__ lab, const int* __restrict__ flag,
                        int* __restrict__ out) {
  int i = blockIdx.x * 256 + threadIdx.x;
  out[i] = flag[0] ? lab[2 * i] : lab[i];
}

// ---- W: L2-normalize rows + cast bf16; pad rows [NCLS,CPAD) with zeros ----
__global__ void prep_w(const float* __restrict__ w, u16* __restrict__ wb) {
  int wv   = threadIdx.x >> 6;
  int lane = threadIdx.x & 63;
  int c = blockIdx.x * 4 + wv;              // one wave per class row
  u16* dst = wb + (size_t)c * DIM + lane * 8;
  if (c >= NCLS) {
    *(uint4*)dst = make_uint4(0, 0, 0, 0);
    return;
  }
  const float* src = w + (size_t)c * DIM + lane * 8;
  float4 v0 = *(const float4*)src;
  float4 v1 = *(const float4*)(src + 4);
  float a[8] = {v0.x, v0.y, v0.z, v0.w, v1.x, v1.y, v1.z, v1.w};
  float ss = 0.f;
  #pragma unroll
  for (int i = 0; i < 8; i++) ss += a[i] * a[i];
  #pragma unroll
  for (int off = 32; off; off >>= 1) ss += __shfl_xor(ss, off, 64);
  float inv = 1.0f / fmaxf(sqrtf(ss), 1e-12f);
  union { u16 h[8]; uint4 q; } pk;
  #pragma unroll
  for (int i = 0; i < 8; i++) pk.h[i] = f2bf(a[i] * inv);
  *(uint4*)dst = pk.q;
}

// ---- E: cast bf16 ----
__global__ void prep_e(const float* __restrict__ e, u16* __restrict__ eb) {
  size_t idx = ((size_t)blockIdx.x * 256 + threadIdx.x) * 8;
  float4 v0 = *(const float4*)(e + idx);
  float4 v1 = *(const float4*)(e + idx + 4);
  float a[8] = {v0.x, v0.y, v0.z, v0.w, v1.x, v1.y, v1.z, v1.w};
  union { u16 h[8]; uint4 q; } pk;
  #pragma unroll
  for (int i = 0; i < 8; i++) pk.h[i] = f2bf(a[i]);
  *(uint4*)(eb + idx) = pk.q;
}

// ---- fused GEMM + clip + margin + partial sum-exp (fixed max = 64) ----
// 2-phase prefetch pipeline: dbuf LDS, next K-step's global_load_lds in
// flight across both barriers (s_waitcnt vmcnt(8), never 0 mid-loop).
// T2 swizzle: linear LDS dest + inverse-swizzled global src + swizzled read.
__global__ __launch_bounds__(256) void arc_main(
    const u16* __restrict__ eb, const u16* __restrict__ wb,
    const int* __restrict__ labels, float* __restrict__ psum,
    float* __restrict__ ll)
{
  __shared__ u16 lA[2][BM * BK];
  __shared__ u16 lB[2][BN * BK];
  const int tid  = threadIdx.x;
  const int lane = tid & 63;
  const int wv   = tid >> 6;
  const int wr   = wv >> 1;       // wave row (0..1): 64 emb rows each
  const int wc   = wv & 1;        // wave col (0..1): 64 classes each

  // XCD-chunked block swizzle: 1504 blocks, 188 consecutive work-items per XCD
  // -> each group's 32 row-blocks land on ONE XCD, sharing its B panel in L2.
  const int bid = blockIdx.x;
  const int nb  = (bid & 7) * (32 * GROUPS / 8) + (bid >> 3);
  const int rb  = nb & 31;
  const int g   = nb >> 5;        // class group 0..46
  const int rowbase = rb * BM;
  const int rgrp = (lane >> 4) * 4;     // D-frag row group
  const int cl   = lane & 15;           // D-frag col lane
  const int hi   = lane >> 4;           // 0..3

  int lbl[4][4];
  #pragma unroll
  for (int m = 0; m < 4; m++)
    #pragma unroll
    for (int j = 0; j < 4; j++)
      lbl[m][j] = labels[rowbase + wr * 64 + m * 16 + rgrp + j];

  float srun[4][4];
  #pragma unroll
  for (int m = 0; m < 4; m++)
    #pragma unroll
    for (int j = 0; j < 4; j++) srun[m][j] = 0.f;

  // staging: lane l of chunk writes LDS linearly at chunk*1024 + l*16 bytes;
  // global source is inverse-swizzled so LDS[r][b] holds global (r, b^(r&7)).
  const int srow = lane >> 3;               // row within 8-row chunk
  const int sb   = (lane & 7) ^ srow;       // swizzled 16B-block index
  u32 abase[4], brow_off[4];
  #pragma unroll
  for (int i = 0; i < 4; i++) {
    const int chunk = wv * 4 + i;
    abase[i]    = (u32)(rowbase + chunk * 8 + srow) * DIM + sb * 8;
    brow_off[i] = (u32)(chunk * 8 + srow) * DIM + sb * 8;
  }

  const float CLIP_HI = 1.0f - 1e-7f;
  const float CLIP_LO = -1.0f + 1e-7f;
  const float COSM = 0.8775825618903728f;   // cos(0.5)
  const float SINM = 0.4794255386042030f;   // sin(0.5)
  const float K1   = 92.33248261972189f;    // 64*log2(e)

  f32x4 acc[4][4];
  #pragma unroll
  for (int m = 0; m < 4; m++)
    #pragma unroll
    for (int n = 0; n < 4; n++)
      #pragma unroll
      for (int q = 0; q < 4; q++) acc[m][n][q] = 0.f;

  // prologue: stage step 0 into buf 0
  {
    const u32 cb0 = (u32)g * BN * DIM;
    #pragma unroll
    for (int i = 0; i < 4; i++) {
      const int chunk = wv * 4 + i;
      gl_lds16(eb + abase[i],        &lA[0][chunk * 512]);
      gl_lds16(wb + cb0 + brow_off[i], &lB[0][chunk * 512]);
    }
  }

  for (int s = 0; s < NSTEPS; s++) {
    const int cur = s & 1;
    if (s + 1 < NSTEPS) {
      const int s1 = s + 1;
      const u32 k1 = (u32)(s1 & 7) * BK;
      const u32 cb1 = (u32)(g + (s1 >> 3) * GROUPS) * BN * DIM;
      #pragma unroll
      for (int i = 0; i < 4; i++) {
        const int chunk = wv * 4 + i;
        gl_lds16(eb + abase[i] + k1,        &lA[cur ^ 1][chunk * 512]);
        gl_lds16(wb + cb1 + brow_off[i] + k1, &lB[cur ^ 1][chunk * 512]);
      }
      asm volatile("s_waitcnt vmcnt(8)" ::: "memory");  // cur's 8 landed; next 8 fly
    } else {
      asm volatile("s_waitcnt vmcnt(0)" ::: "memory");
    }
    __builtin_amdgcn_s_barrier();
    asm volatile("" ::: "memory");

    const u16* As = lA[cur];
    const u16* Bs = lB[cur];
    #pragma unroll
    for (int kk = 0; kk < 2; kk++) {
      bf16x8 af[4], bg[4];
      const int b = kk * 4 + hi;
      #pragma unroll
      for (int m = 0; m < 4; m++) {
        const int r = wr * 64 + m * 16 + cl;
        af[m] = *(const bf16x8*)&As[r * 64 + ((b ^ (r & 7)) << 3)];
      }
      #pragma unroll
      for (int n = 0; n < 4; n++) {
        const int r = wc * 64 + n * 16 + cl;
        bg[n] = *(const bf16x8*)&Bs[r * 64 + ((b ^ (r & 7)) << 3)];
      }
      #pragma unroll
      for (int m = 0; m < 4; m++)
        #pragma unroll
        for (int n = 0; n < 4; n++)
          acc[m][n] = __builtin_amdgcn_mfma_f32_16x16x32_bf16(af[m], bg[n], acc[m][n], 0, 0, 0);
    }
    __builtin_amdgcn_s_barrier();   // all waves done reading buf[cur]
    asm volatile("" ::: "memory");

    if ((s & 7) == 7) {
      // epilogue for tile tt: clip, margin-at-label, accumulate exp(logit-64)
      const int tt = s >> 3;
      const int cbT = (g + tt * GROUPS) * BN;
      #pragma unroll
      for (int n = 0; n < 4; n++) {
        const int cidx = cbT + wc * 64 + n * 16 + cl;
        #pragma unroll
        for (int m = 0; m < 4; m++) {
          #pragma unroll
          for (int j = 0; j < 4; j++) {
            float v  = acc[m][n][j];
            float tc = __builtin_amdgcn_fmed3f(v, CLIP_LO, CLIP_HI);
            float tv = tc;
            if (lbl[m][j] == cidx) {
              float sq = __builtin_amdgcn_sqrtf(fmaxf(1.0f - tc * tc, 0.0f));
              tv = tc * COSM - sq * SINM;
              ll[rowbase + wr * 64 + m * 16 + rgrp + j] = tv * 64.0f;
            }
            srun[m][j] += __builtin_amdgcn_exp2f(__builtin_fmaf(tv, K1, -K1));
          }
        }
      }
      #pragma unroll
      for (int m = 0; m < 4; m++)
        #pragma unroll
        for (int n = 0; n < 4; n++)
          #pragma unroll
          for (int q = 0; q < 4; q++) acc[m][n][q] = 0.f;
    }
  }

  // reduce partial sums across the 16 col-lanes, one partial per row
  #pragma unroll
  for (int m = 0; m < 4; m++) {
    #pragma unroll
    for (int j = 0; j < 4; j++) {
      float s = srun[m][j];
      s += __shfl_xor(s, 1, 64);
      s += __shfl_xor(s, 2, 64);
      s += __shfl_xor(s, 4, 64);
      s += __shfl_xor(s, 8, 64);
      if (cl == 0)
        psum[(size_t)(g * 2 + wc) * N_ROWS + rowbase + wr * 64 + m * 16 + rgrp + j] = s;
    }
  }
}

// ---- per-row LSE merge + per-block loss sums ----
__global__ void arc_finish1(const float* __restrict__ psum, const float* __restrict__ ll,
                            float* __restrict__ bl) {
  int tid = threadIdx.x;
  int row = blockIdx.x * 256 + tid;
  float S = 0.f;
  #pragma unroll
  for (int p = 0; p < NPART; p++) S += psum[(size_t)p * N_ROWS + row];
  float loss = 64.0f + __builtin_amdgcn_logf(S) * 0.6931471805599453f - ll[row];
  #pragma unroll
  for (int off = 32; off; off >>= 1) loss += __shfl_xor(loss, off, 64);
  __shared__ float red[4];
  if ((tid & 63) == 0) red[tid >> 6] = loss;
  __syncthreads();
  if (tid == 0) bl[blockIdx.x] = red[0] + red[1] + red[2] + red[3];
}

__global__ void arc_finish2(const float* __restrict__ bl, float* __restrict__ out) {
  if (threadIdx.x == 0) {
    float t = 0.f;
    for (int i = 0; i < N_ROWS / 256; i++) t += bl[i];
    out[0] = t * (1.0f / (float)N_ROWS);
  }
}

extern "C" void kernel_launch(void* const* d_in, const int* in_sizes, int n_in,
                              void* d_out, int out_size, void* d_ws, size_t ws_size,
                              hipStream_t stream) {
  const float* emb   = (const float*)d_in[0];
  const int*   lab   = (const int*)d_in[1];
  const float* wts   = (const float*)d_in[2];

  char* ws = (char*)d_ws;
  u16*   wb    = (u16*)(ws);
  u16*   eb    = (u16*)(ws + WB_BYTES);
  float* psum  = (float*)(ws + WB_BYTES + EB_BYTES);
  float* ll    = (float*)(ws + WB_BYTES + EB_BYTES + PSUM_BYTES);
  float* bl    = (float*)(ws + WB_BYTES + EB_BYTES + PSUM_BYTES + LL_BYTES);
  int*   lab32 = (int*)  (ws + WB_BYTES + EB_BYTES + PSUM_BYTES + LL_BYTES + BL_BYTES);
  int*   flag  = (int*)  (ws + WB_BYTES + EB_BYTES + PSUM_BYTES + LL_BYTES + BL_BYTES + LAB_BYTES);
  // total ~36.6 MiB of d_ws assumed available

  lab_detect<<<dim3(1), dim3(1024), 0, stream>>>(lab, flag);
  lab_fix<<<dim3(N_ROWS / 256), dim3(256), 0, stream>>>(lab, flag, lab32);
  prep_w<<<dim3(CPAD / 4), dim3(256), 0, stream>>>(wts, wb);
  prep_e<<<dim3((N_ROWS * DIM / 8) / 256), dim3(256), 0, stream>>>(emb, eb);
  arc_main<<<dim3(32 * GROUPS), dim3(256), 0, stream>>>(eb, wb, lab32, psum, ll);
  arc_finish1<<<dim3(N_ROWS / 256), dim3(256), 0, stream>>>(psum, ll, bl);
  arc_finish2<<<dim3(1), dim3(64), 0, stream>>>(bl, (float*)d_out);
}

// Round 3
// 214.787 us; speedup vs baseline: 1.8719x; 1.8404x over previous
//
#include <hip/hip_runtime.h>
#include <cstdint>
#include <cstddef>

// Problem constants (fixed by the reference)
#define N_ROWS 4096
#define DIM    512
#define NCLS   30000
#define BM 256
#define BN 256
#define BK 32
#define NT2  118                    // ceil(30000/256) N-tiles
#define CPAD (NT2 * 256)            // 30208, padded classes (zero rows)
#define SPT 2                       // N-tiles per block strip
#define NSTRIPS (NT2 / SPT)         // 59
#define KT  (DIM / BK)              // 16 K-tiles per N-tile
#define NS  (SPT * KT)              // 32 steps per block

typedef float  f32x4  __attribute__((ext_vector_type(4)));
typedef short  bf16x8 __attribute__((ext_vector_type(8)));
typedef unsigned int   u32;
typedef unsigned short u16;

// ---- workspace layout (bytes) ----
#define WB_BYTES   ((size_t)CPAD * DIM * 2)     // 30,932,992
#define EB_BYTES   ((size_t)N_ROWS * DIM * 2)   //  4,194,304
#define PS_BYTES   ((size_t)NT2 * N_ROWS * 4)   //  1,933,312
#define CT_BYTES   ((size_t)N_ROWS * 4)
#define BL_BYTES   (64 * 4)
#define LAB_BYTES  ((size_t)N_ROWS * 4)

#define CLIP_HI ( 1.0f - 1e-7f)
#define CLIP_LO (-1.0f + 1e-7f)
#define COSM 0.8775825618903728f    // cos(0.5)
#define SINM 0.4794255386042030f    // sin(0.5)
#define K1   92.33248261972189f     // 64*log2(e): exp(64c-64) = 2^((c-1)*K1)

__device__ __forceinline__ u16 f2bf(float f) {  // RNE float->bf16
  u32 x = __builtin_bit_cast(u32, f);
  x += 0x7fffu + ((x >> 16) & 1u);
  return (u16)(x >> 16);
}

__device__ __forceinline__ void gl_lds16(const u16* g, u16* l) {
  __builtin_amdgcn_global_load_lds((const __attribute__((address_space(1))) u32*)g,
                                   (__attribute__((address_space(3))) u32*)l,
                                   16, 0, 0);
}

// ---- label dtype probe: int64 little-endian reads as [lo,0,lo,0,...] ----
__global__ void lab_detect(const int* __restrict__ lab, int* __restrict__ flag) {
  __shared__ int s_nz;
  int tid = threadIdx.x;
  if (tid == 0) s_nz = 0;
  __syncthreads();
  int nz = 0;
  for (int i = tid; i < N_ROWS / 2; i += 1024) nz |= lab[2 * i + 1];
  if (nz) atomicOr(&s_nz, 1);
  __syncthreads();
  if (tid == 0) *flag = (s_nz == 0) ? 1 : 0;   // 1 -> int64 layout
}

__global__ void lab_fix(const int* __restrict__ lab, const int* __restrict__ flag,
                        int* __restrict__ out) {
  int i = blockIdx.x * 256 + threadIdx.x;
  out[i] = flag[0] ? lab[2 * i] : lab[i];
}

// ---- W: L2-normalize rows + cast bf16; pad rows [NCLS,CPAD) with zeros ----
__global__ void prep_w(const float* __restrict__ w, u16* __restrict__ wb) {
  int wv   = threadIdx.x >> 6;
  int lane = threadIdx.x & 63;
  int c = blockIdx.x * 4 + wv;              // one wave per class row
  u16* dst = wb + (size_t)c * DIM + lane * 8;
  if (c >= NCLS) {
    *(uint4*)dst = make_uint4(0, 0, 0, 0);
    return;
  }
  const float* src = w + (size_t)c * DIM + lane * 8;
  float4 v0 = *(const float4*)src;
  float4 v1 = *(const float4*)(src + 4);
  float a[8] = {v0.x, v0.y, v0.z, v0.w, v1.x, v1.y, v1.z, v1.w};
  float ss = 0.f;
  #pragma unroll
  for (int i = 0; i < 8; i++) ss += a[i] * a[i];
  #pragma unroll
  for (int off = 32; off; off >>= 1) ss += __shfl_xor(ss, off, 64);
  float inv = 1.0f / fmaxf(sqrtf(ss), 1e-12f);
  union { u16 h[8]; uint4 q; } pk;
  #pragma unroll
  for (int i = 0; i < 8; i++) pk.h[i] = f2bf(a[i] * inv);
  *(uint4*)dst = pk.q;
}

// ---- E: cast bf16 ----
__global__ void prep_e(const float* __restrict__ e, u16* __restrict__ eb) {
  size_t idx = ((size_t)blockIdx.x * 256 + threadIdx.x) * 8;
  float4 v0 = *(const float4*)(e + idx);
  float4 v1 = *(const float4*)(e + idx + 4);
  float a[8] = {v0.x, v0.y, v0.z, v0.w, v1.x, v1.y, v1.z, v1.w};
  union { u16 h[8]; uint4 q; } pk;
  #pragma unroll
  for (int i = 0; i < 8; i++) pk.h[i] = f2bf(a[i]);
  *(uint4*)(eb + idx) = pk.q;
}

// ---- target cosine per row, f32: dot(emb[n], w[lab[n]]/||w[lab[n]]||) ----
__global__ void tgt_k(const float* __restrict__ emb, const float* __restrict__ wts,
                      const int* __restrict__ lab, float* __restrict__ ct) {
  int w = threadIdx.x >> 6, l = threadIdx.x & 63;
  int row = blockIdx.x * 4 + w;
  int c = lab[row];
  const float* e  = emb + (size_t)row * DIM + l * 8;
  const float* wp = wts + (size_t)c   * DIM + l * 8;
  float4 e0 = *(const float4*)e,       e1 = *(const float4*)(e + 4);
  float4 w0 = *(const float4*)wp,      w1 = *(const float4*)(wp + 4);
  float dot = e0.x*w0.x + e0.y*w0.y + e0.z*w0.z + e0.w*w0.w
            + e1.x*w1.x + e1.y*w1.y + e1.z*w1.z + e1.w*w1.w;
  float ss  = w0.x*w0.x + w0.y*w0.y + w0.z*w0.z + w0.w*w0.w
            + w1.x*w1.x + w1.y*w1.y + w1.z*w1.z + w1.w*w1.w;
  #pragma unroll
  for (int off = 32; off; off >>= 1) {
    dot += __shfl_xor(dot, off, 64);
    ss  += __shfl_xor(ss,  off, 64);
  }
  if (l == 0) ct[row] = dot / fmaxf(sqrtf(ss), 1e-12f);
}

// ---- fused GEMM + clip + partial sum-exp (fixed max = 64), 256x256 tile ----
// 8 waves (2m x 4n); 3-stage LDS pipeline, one barrier + vmcnt(4) per K-tile.
// Stage tile u+2 while computing u (overwrites u-1's buf: reads done pre-barrier).
__global__ __launch_bounds__(512, 2) void arc_main(
    const u16* __restrict__ eb, const u16* __restrict__ wb,
    float* __restrict__ psum)
{
  __shared__ __align__(16) u16 lA[3][BM * BK];
  __shared__ __align__(16) u16 lB[3][BN * BK];
  __shared__ float ep[4][BM];
  const int tid = threadIdx.x;
  const int l   = tid & 63;
  const int w   = tid >> 6;
  const int wm  = w >> 2, wn = w & 3;
  const int mi    = blockIdx.x & 15;    // m inner: concurrent blocks share E in L3
  const int strip = blockIdx.x >> 4;
  const int rowbase = mi * BM;
  const int n0 = strip * SPT;

  // frag LDS elem offsets; 16B-slot swizzle b' = b ^ ((r>>1)&3) -> 2-way (free)
  u32 aoff[8], boff[4];
  const int bq = l >> 4;
  #pragma unroll
  for (int m = 0; m < 8; m++) {
    int r = wm * 128 + m * 16 + (l & 15);
    aoff[m] = (u32)r * BK + ((bq ^ ((r >> 1) & 3)) << 3);
  }
  #pragma unroll
  for (int n = 0; n < 4; n++) {
    int r = wn * 64 + n * 16 + (l & 15);
    boff[n] = (u32)r * BK + ((bq ^ ((r >> 1) & 3)) << 3);
  }

  // staging: waves 0-3 -> A, waves 4-7 -> B; 4 chunks of 1KB each; linear LDS
  // dest + inverse-swizzled global source (same involution as the read).
  const int sch = (w & 3) * 4;
  u32 goff[4];
  #pragma unroll
  for (int i = 0; i < 4; i++) {
    int rl = (sch + i) * 16 + (l >> 2);
    goff[i] = (u32)rl * DIM + (((l & 3) ^ ((rl >> 1) & 3)) << 3);
  }
  const bool isA = (w < 4);
  const u16* gsrc = isA ? (eb + (size_t)rowbase * DIM) : wb;
  u16* lds0 = isA ? &lA[0][0] : &lB[0][0];

  #define STAGE(u_) do {                                                     \
    const int buf_ = (u_) % 3;                                               \
    const u32 base_ = isA ? (u32)(((u_) & 15) * BK)                          \
        : (u32)(n0 + ((u_) >> 4)) * BN * DIM + (u32)(((u_) & 15) * BK);      \
    u16* dst_ = lds0 + buf_ * (BM * BK) + sch * 512;                         \
    _Pragma("unroll")                                                        \
    for (int i_ = 0; i_ < 4; i_++)                                           \
      gl_lds16(gsrc + base_ + goff[i_], dst_ + i_ * 512);                    \
  } while (0)

  f32x4 acc[8][4];
  #pragma unroll
  for (int m = 0; m < 8; m++)
    #pragma unroll
    for (int n = 0; n < 4; n++)
      #pragma unroll
      for (int q = 0; q < 4; q++) acc[m][n][q] = 0.f;

  STAGE(0);
  STAGE(1);

  for (int u = 0; u < NS; u++) {
    if (u < NS - 1) asm volatile("s_waitcnt vmcnt(4)" ::: "memory");
    else            asm volatile("s_waitcnt vmcnt(0)" ::: "memory");
    __builtin_amdgcn_s_barrier();
    asm volatile("" ::: "memory");
    if (u + 2 < NS) STAGE(u + 2);

    const int buf = u % 3;
    bf16x8 af[8], bg[4];
    #pragma unroll
    for (int m = 0; m < 8; m++) af[m] = *(const bf16x8*)&lA[buf][aoff[m]];
    #pragma unroll
    for (int n = 0; n < 4; n++) bg[n] = *(const bf16x8*)&lB[buf][boff[n]];

    __builtin_amdgcn_s_setprio(1);
    #pragma unroll
    for (int m = 0; m < 8; m++)
      #pragma unroll
      for (int n = 0; n < 4; n++)
        acc[m][n] = __builtin_amdgcn_mfma_f32_16x16x32_bf16(af[m], bg[n], acc[m][n], 0, 0, 0);
    __builtin_amdgcn_s_setprio(0);

    if ((u & 15) == 15) {
      // epilogue for N-tile nt: clip, exp2, sum over this wave's 64 cols,
      // cross-wn merge via LDS, one psum row-partial per N-tile.
      const int nt = n0 + (u >> 4);
      #pragma unroll
      for (int m = 0; m < 8; m++) {
        #pragma unroll
        for (int q = 0; q < 4; q++) {
          float s = 0.f;
          #pragma unroll
          for (int n = 0; n < 4; n++) {
            float tc = __builtin_amdgcn_fmed3f(acc[m][n][q], CLIP_LO, CLIP_HI);
            s += __builtin_amdgcn_exp2f(__builtin_fmaf(tc, K1, -K1));
            acc[m][n][q] = 0.f;
          }
          s += __shfl_xor(s, 1, 64);
          s += __shfl_xor(s, 2, 64);
          s += __shfl_xor(s, 4, 64);
          s += __shfl_xor(s, 8, 64);
          if ((l & 15) == 0) ep[wn][wm * 128 + m * 16 + (l >> 4) * 4 + q] = s;
        }
      }
      asm volatile("s_waitcnt lgkmcnt(0)" ::: "memory");
      __builtin_amdgcn_s_barrier();
      asm volatile("" ::: "memory");
      if (l < 32) {
        int r = w * 32 + l;
        float t = ep[0][r] + ep[1][r] + ep[2][r] + ep[3][r];
        psum[(size_t)nt * N_ROWS + rowbase + r] = t;
      }
    }
  }
  #undef STAGE
}

// ---- per-row LSE merge + margin swap + per-block loss sums ----
__global__ void arc_finish1(const float* __restrict__ psum, const float* __restrict__ ct,
                            float* __restrict__ bl) {
  int tid = threadIdx.x;
  int row = blockIdx.x * 256 + tid;
  float S = 0.f;
  for (int p = 0; p < NT2; p++) S += psum[(size_t)p * N_ROWS + row];
  float c  = __builtin_amdgcn_fmed3f(ct[row], CLIP_LO, CLIP_HI);
  float cm = c * COSM - sqrtf(fmaxf(1.0f - c * c, 0.0f)) * SINM;
  // swap the target's no-margin term for the margin term (both vs fixed max 64)
  float S2 = S - __builtin_amdgcn_exp2f(__builtin_fmaf(c,  K1, -K1))
               + __builtin_amdgcn_exp2f(__builtin_fmaf(cm, K1, -K1));
  float loss = 64.0f + __builtin_amdgcn_logf(S2) * 0.6931471805599453f - 64.0f * cm;
  #pragma unroll
  for (int off = 32; off; off >>= 1) loss += __shfl_xor(loss, off, 64);
  __shared__ float red[4];
  if ((tid & 63) == 0) red[tid >> 6] = loss;
  __syncthreads();
  if (tid == 0) bl[blockIdx.x] = red[0] + red[1] + red[2] + red[3];
}

__global__ void arc_finish2(const float* __restrict__ bl, float* __restrict__ out) {
  if (threadIdx.x == 0) {
    float t = 0.f;
    for (int i = 0; i < N_ROWS / 256; i++) t += bl[i];
    out[0] = t * (1.0f / (float)N_ROWS);
  }
}

extern "C" void kernel_launch(void* const* d_in, const int* in_sizes, int n_in,
                              void* d_out, int out_size, void* d_ws, size_t ws_size,
                              hipStream_t stream) {
  const float* emb   = (const float*)d_in[0];
  const int*   lab   = (const int*)d_in[1];
  const float* wts   = (const float*)d_in[2];

  char* ws = (char*)d_ws;
  u16*   wb    = (u16*)(ws);
  u16*   eb    = (u16*)(ws + WB_BYTES);
  float* psum  = (float*)(ws + WB_BYTES + EB_BYTES);
  float* ct    = (float*)(ws + WB_BYTES + EB_BYTES + PS_BYTES);
  float* bl    = (float*)(ws + WB_BYTES + EB_BYTES + PS_BYTES + CT_BYTES);
  int*   lab32 = (int*)  (ws + WB_BYTES + EB_BYTES + PS_BYTES + CT_BYTES + BL_BYTES);
  int*   flag  = (int*)  (ws + WB_BYTES + EB_BYTES + PS_BYTES + CT_BYTES + BL_BYTES + LAB_BYTES);
  // total ~37.1 MiB of d_ws assumed available

  lab_detect<<<dim3(1), dim3(1024), 0, stream>>>(lab, flag);
  lab_fix<<<dim3(N_ROWS / 256), dim3(256), 0, stream>>>(lab, flag, lab32);
  prep_w<<<dim3(CPAD / 4), dim3(256), 0, stream>>>(wts, wb);
  prep_e<<<dim3((N_ROWS * DIM / 8) / 256), dim3(256), 0, stream>>>(emb, eb);
  tgt_k<<<dim3(N_ROWS / 4), dim3(256), 0, stream>>>(emb, wts, lab32, ct);
  arc_main<<<dim3(16 * NSTRIPS), dim3(512), 0, stream>>>(eb, wb, psum);
  arc_finish1<<<dim3(N_ROWS / 256), dim3(256), 0, stream>>>(psum, ct, bl);
  arc_finish2<<<dim3(1), dim3(64), 0, stream>>>(bl, (float*)d_out);
}